// Round 17
// baseline (93.564 us; speedup 1.0000x reference)
//
#include <hip/hip_runtime.h>

#define N_NODES  100000
#define N_EDGES  1600000
#define N_GRAPHS 128
#define DD       64
#define EPSV     1e-5f

#define BSH      5          // bucket = dst >> 5  (32 nodes per bucket)
#define BMASK    31
#define NBUCK    3125       // 100000/32 exactly
#define CAPB     768        // slab capacity: mean 512, sigma 22.6 -> 11 sigma margin

#define THRP     1024       // scatter block threads
#define EPT      16         // edges per thread (98 blocks — known-good)
#define BLKE     (THRP*EPT) // 16384
#define NBLK     ((N_EDGES + BLKE - 1) / BLKE)   // 98

// workspace byte offsets
#define O_CUR   0u          // int[NBUCK*16]
#define O_BKT   200704u     // int[NBUCK*CAPB] packed (dstlo<<17)|src
#define O_GACC  9801216u    // float[G*D]; bytes [9833984,9834496) = zero row (gather tail target)
#define O_XB    9834496u    // ushort[N_NODES*DD]  bf16 copy of x
#define O_WTF   22634496u   // ushort[1024*8]  B-operand in MFMA fragment layout (16 KB)
#define WS_NEED (O_WTF + 16384u)

typedef __attribute__((ext_vector_type(8))) short bf16x8;
typedef __attribute__((ext_vector_type(4))) float f32x4;
typedef __attribute__((ext_vector_type(2))) float f32x2;

__device__ __forceinline__ ushort bf16rne(float f) {
  uint u = __float_as_uint(f);
  return (ushort)((u + 0x7FFFu + ((u >> 16) & 1u)) >> 16);
}
__device__ __forceinline__ uint pk2(float lo, float hi) {
  return (uint)bf16rne(lo) | ((uint)bf16rne(hi) << 16);
}

// full-grid fp32->bf16 cast of x + zero-init of cur, gacc, and the 512B zero row
__global__ __launch_bounds__(256) void cast_k(const float* __restrict__ x, ushort* __restrict__ xb,
                                              int* __restrict__ cur, float* __restrict__ gacc) {
  int i = blockIdx.x * 256 + threadIdx.x;      // grid 6250*256 = 1.6M = N_NODES*DD/4 exactly
  if (i < NBUCK * 16) cur[i] = 0;
  if (i < N_GRAPHS * DD) gacc[i] = 0.f;
  if (i < 128) gacc[N_GRAPHS * DD + i] = 0.f;  // zero row gap at ws+9833984 (= xb - 512)
  float4 v = ((const float4*)x)[i];
  uint4 u = *(const uint4*)&v;
  ushort4 o;
  o.x = (ushort)((u.x + 0x7FFFu + ((u.x >> 16) & 1)) >> 16);
  o.y = (ushort)((u.y + 0x7FFFu + ((u.y >> 16) & 1)) >> 16);
  o.z = (ushort)((u.z + 0x7FFFu + ((u.z >> 16) & 1)) >> 16);
  o.w = (ushort)((u.w + 0x7FFFu + ((u.w >> 16) & 1)) >> 16);
  ((ushort4*)xb)[i] = o;
}

// block-staged two-pass scatter; block 0 also builds the MFMA B-operand image wtf.
// hist[] reused in place: counts -> (after reservation) live slab cursor.
__global__ __launch_bounds__(1024) void scatP_k(const int* __restrict__ ei, int* __restrict__ cur,
                                                int* __restrict__ bkt,
                                                const float* __restrict__ Wself,
                                                const float* __restrict__ Wneigh,
                                                ushort* __restrict__ wtf) {
  __shared__ int hist[NBUCK];
  int t = threadIdx.x;
  if (blockIdx.x == 0) {
    // fragment f=(nt,tile,ks,lane): 8 bf16 of WT[nt*32+tile*16+(lane&15)][ks*32+(lane>>4)*8+j]
    int lane = t & 63, ks = (t >> 6) & 3, tile = (t >> 8) & 1, nt = t >> 9;
    int brow = (nt << 5) + (tile << 4) + (lane & 15);
    int k0 = (ks << 5) + (((lane >> 4) & 3) << 3);
    uint4 o;
    uint p[4];
#pragma unroll
    for (int jj = 0; jj < 4; ++jj) {
      int k = k0 + jj * 2;
      float w0 = (k < 64)     ? Wself[k * DD + brow]       : Wneigh[(k - 64) * DD + brow];
      float w1 = (k + 1 < 64) ? Wself[(k + 1) * DD + brow] : Wneigh[(k - 63) * DD + brow];
      p[jj] = pk2(w0, w1);
    }
    o.x = p[0]; o.y = p[1]; o.z = p[2]; o.w = p[3];
    ((uint4*)wtf)[t] = o;
  }
  for (int i = t; i < NBUCK; i += THRP) hist[i] = 0;
  __syncthreads();
  int e0 = blockIdx.x * BLKE;
  int pk[EPT], bn[EPT];
#pragma unroll
  for (int j = 0; j < EPT; ++j) {
    int e = e0 + j * THRP + t;
    bn[j] = -1;
    if (e < N_EDGES) {
      int s = ei[e], d = ei[N_EDGES + e];
      bn[j] = d >> BSH;
      pk[j] = s | ((d & BMASK) << 17);
      atomicAdd(&hist[bn[j]], 1);
    }
  }
  __syncthreads();
  for (int b = t; b < NBUCK; b += THRP) {     // each b handled by exactly one thread
    int c = hist[b];
    hist[b] = c ? atomicAdd(&cur[b * 16], c) : 0;   // count -> live slab cursor
  }
  __syncthreads();
#pragma unroll
  for (int j = 0; j < EPT; ++j) {
    if (bn[j] >= 0) {
      int sp = atomicAdd(&hist[bn[j]], 1);    // slab-relative position
      if (sp < CAPB) bkt[bn[j] * CAPB + sp] = pk[j];
    }
  }
}

// FUSED per-bucket kernel: counting-sort (premultiplied byte offsets) -> two-row
// interleaved pull-based mean (8 gathers in flight) -> MFMA combine -> epilogue.
__global__ __launch_bounds__(256, 8) void aggM_k(const ushort* __restrict__ xb,
                                                 const int* __restrict__ cur,
                                                 const int* __restrict__ bkt,
                                                 const ushort* __restrict__ wtf,
                                                 const float* __restrict__ bvec,
                                                 const float* __restrict__ gamma,
                                                 const float* __restrict__ beta,
                                                 const int* __restrict__ batch,
                                                 float* __restrict__ gacc,
                                                 float* __restrict__ out) {
  __shared__ short As[32 * 128];    // 8KB: A=[xb|h] bf16 swizzled; LIVE through epilogue
  __shared__ float Cbuf[32 * 65];   // 8.3KB: MFMA C, padded row stride (conflict-free reads)
  __shared__ int sorted[CAPB + 64]; // byte offsets (idx*128+512), +64 pad for pair-loop reads
  __shared__ int hist[32], startc[32], curl[32];
  int t = threadIdx.x;
  int b = blockIdx.x;
  int node0 = b << BSH;
  if (t < 32) hist[t] = 0;
  // stage A x-part (k=0..63): contiguous 4KB read of this bucket's xb rows
  {
    uint4 v = ((const uint4*)(xb + (size_t)node0 * DD))[t];   // t = r*8 + c
    uint r = (uint)t >> 3, c = (uint)t & 7;
    *(uint4*)((char*)As + r * 256u + ((c * 16u) ^ ((r & 7u) << 4))) = v;
  }
  __syncthreads();
  int n = cur[b * 16];
  if (n > CAPB) n = CAPB;
  int boff = b * CAPB;
  int w0 = -1, w1 = -1, w2 = -1;
  if (t < n)       { w0 = bkt[boff + t];       atomicAdd(&hist[w0 >> 17], 1); }
  if (t + 256 < n) { w1 = bkt[boff + t + 256]; atomicAdd(&hist[w1 >> 17], 1); }
  if (t + 512 < n) { w2 = bkt[boff + t + 512]; atomicAdd(&hist[w2 >> 17], 1); }
  __syncthreads();
  // exclusive scan of 32 bins: wave-0 shuffle scan, ONE barrier
  if (t < 32) {
    int h = hist[t];
    int v = h;
#pragma unroll
    for (int off = 1; off < 32; off <<= 1) {
      int u = __shfl_up(v, off);
      if (t >= off) v += u;
    }
    startc[t] = v - h;
    curl[t]   = v - h;
  }
  __syncthreads();
  if (w0 >= 0) { int p = atomicAdd(&curl[w0 >> 17], 1); sorted[p] = ((w0 & 0x1FFFF) << 7) + 512; }
  if (w1 >= 0) { int p = atomicAdd(&curl[w1 >> 17], 1); sorted[p] = ((w1 & 0x1FFFF) << 7) + 512; }
  if (w2 >= 0) { int p = atomicAdd(&curl[w2 >> 17], 1); sorted[p] = ((w2 & 0x1FFFF) << 7) + 512; }
  __syncthreads();
  int wl   = __builtin_amdgcn_readfirstlane(t >> 6);
  int lane = t & 63;
  int g    = lane >> 4;     // edge-group 0..3
  int sub  = lane & 15;     // dim group: dims [sub*4, sub*4+4)
  const char* zb = (const char*)xb - 512;   // base: +0 hits the zero row, +sorted hits xb
  uint subb = (uint)sub * 8u;
  // two-row interleaved pull aggregation: rows (rA, rA+16), 8 gathers in flight
  for (int pr = 0; pr < 4; ++pr) {
    int rA = wl + pr * 4, rB = rA + 16;
    int sA = startc[rA], dA = hist[rA];
    int sB = startc[rB], dB = hist[rB];
    f32x2 A01 = {0.f, 0.f}, A23 = {0.f, 0.f};
    f32x2 B01 = {0.f, 0.f}, B23 = {0.f, 0.f};
    int dmax = dA > dB ? dA : dB;
    for (int j = 0; j < dmax; j += 16) {
      int e0 = j + g, e1 = j + 4 + g, e2 = j + 8 + g, e3 = j + 12 + g;
      // index-clamped sorted reads (always in-bounds), offset-select -> zero row on tail
      uint a0 = (uint)sorted[sA + (e0 < dA ? e0 : 0)]; if (e0 >= dA) a0 = 0u;
      uint a1 = (uint)sorted[sA + (e1 < dA ? e1 : 0)]; if (e1 >= dA) a1 = 0u;
      uint a2 = (uint)sorted[sA + (e2 < dA ? e2 : 0)]; if (e2 >= dA) a2 = 0u;
      uint a3 = (uint)sorted[sA + (e3 < dA ? e3 : 0)]; if (e3 >= dA) a3 = 0u;
      uint b0 = (uint)sorted[sB + (e0 < dB ? e0 : 0)]; if (e0 >= dB) b0 = 0u;
      uint b1 = (uint)sorted[sB + (e1 < dB ? e1 : 0)]; if (e1 >= dB) b1 = 0u;
      uint b2 = (uint)sorted[sB + (e2 < dB ? e2 : 0)]; if (e2 >= dB) b2 = 0u;
      uint b3 = (uint)sorted[sB + (e3 < dB ? e3 : 0)]; if (e3 >= dB) b3 = 0u;
      uint2 uA0 = *(const uint2*)(zb + a0 + subb);   // 8 independent gathers in flight
      uint2 uA1 = *(const uint2*)(zb + a1 + subb);
      uint2 uA2 = *(const uint2*)(zb + a2 + subb);
      uint2 uA3 = *(const uint2*)(zb + a3 + subb);
      uint2 uB0 = *(const uint2*)(zb + b0 + subb);
      uint2 uB1 = *(const uint2*)(zb + b1 + subb);
      uint2 uB2 = *(const uint2*)(zb + b2 + subb);
      uint2 uB3 = *(const uint2*)(zb + b3 + subb);
      f32x2 v0, v1, v2, v3;
      v0.x = __uint_as_float(uA0.x << 16); v0.y = __uint_as_float(uA0.x & 0xFFFF0000u);
      v1.x = __uint_as_float(uA1.x << 16); v1.y = __uint_as_float(uA1.x & 0xFFFF0000u);
      v2.x = __uint_as_float(uA2.x << 16); v2.y = __uint_as_float(uA2.x & 0xFFFF0000u);
      v3.x = __uint_as_float(uA3.x << 16); v3.y = __uint_as_float(uA3.x & 0xFFFF0000u);
      A01 += (v0 + v1) + (v2 + v3);
      v0.x = __uint_as_float(uA0.y << 16); v0.y = __uint_as_float(uA0.y & 0xFFFF0000u);
      v1.x = __uint_as_float(uA1.y << 16); v1.y = __uint_as_float(uA1.y & 0xFFFF0000u);
      v2.x = __uint_as_float(uA2.y << 16); v2.y = __uint_as_float(uA2.y & 0xFFFF0000u);
      v3.x = __uint_as_float(uA3.y << 16); v3.y = __uint_as_float(uA3.y & 0xFFFF0000u);
      A23 += (v0 + v1) + (v2 + v3);
      v0.x = __uint_as_float(uB0.x << 16); v0.y = __uint_as_float(uB0.x & 0xFFFF0000u);
      v1.x = __uint_as_float(uB1.x << 16); v1.y = __uint_as_float(uB1.x & 0xFFFF0000u);
      v2.x = __uint_as_float(uB2.x << 16); v2.y = __uint_as_float(uB2.x & 0xFFFF0000u);
      v3.x = __uint_as_float(uB3.x << 16); v3.y = __uint_as_float(uB3.x & 0xFFFF0000u);
      B01 += (v0 + v1) + (v2 + v3);
      v0.x = __uint_as_float(uB0.y << 16); v0.y = __uint_as_float(uB0.y & 0xFFFF0000u);
      v1.x = __uint_as_float(uB1.y << 16); v1.y = __uint_as_float(uB1.y & 0xFFFF0000u);
      v2.x = __uint_as_float(uB2.y << 16); v2.y = __uint_as_float(uB2.y & 0xFFFF0000u);
      v3.x = __uint_as_float(uB3.y << 16); v3.y = __uint_as_float(uB3.y & 0xFFFF0000u);
      B23 += (v0 + v1) + (v2 + v3);
    }
    float a0 = A01.x, a1 = A01.y, a2 = A23.x, a3 = A23.y;
    float b0 = B01.x, b1 = B01.y, b2 = B23.x, b3 = B23.y;
    // merge the 4 edge-groups: butterfly over lane bits 4,5 (both rows interleaved)
#pragma unroll
    for (int off = 16; off <= 32; off <<= 1) {
      a0 += __shfl_xor(a0, off);
      a1 += __shfl_xor(a1, off);
      a2 += __shfl_xor(a2, off);
      a3 += __shfl_xor(a3, off);
      b0 += __shfl_xor(b0, off);
      b1 += __shfl_xor(b1, off);
      b2 += __shfl_xor(b2, off);
      b3 += __shfl_xor(b3, off);
    }
    if (g == 0) {
      float invA = 1.f / fmaxf((float)dA, 1.f);
      float invB = 1.f / fmaxf((float)dB, 1.f);
      uint2 pw;
      pw.x = pk2(a0 * invA, a1 * invA);
      pw.y = pk2(a2 * invA, a3 * invA);
      uint rr = (uint)rA;
      *(uint2*)((char*)As + rr * 256u + ((128u + (uint)sub * 8u) ^ ((rr & 7u) << 4))) = pw;
      pw.x = pk2(b0 * invB, b1 * invB);
      pw.y = pk2(b2 * invB, b3 * invB);
      rr = (uint)rB;
      *(uint2*)((char*)As + rr * 256u + ((128u + (uint)sub * 8u) ^ ((rr & 7u) << 4))) = pw;
    }
  }
  __syncthreads();
  // MFMA combine: wave -> (mrow, n-tile pair); B fragments streamed from global (L2-hot),
  // unroll 1 keeps the loads in-loop so peak VGPR stays within the 8-blocks/CU budget.
  f32x4 acc0 = {0.f, 0.f, 0.f, 0.f}, acc1 = {0.f, 0.f, 0.f, 0.f};
  uint mrow  = (uint)(wl >> 1) << 4;   // 0 / 16
  int  nt    = wl & 1;
  uint arow  = mrow + (uint)(lane & 15);
  uint kc    = ((uint)(lane >> 4)) * 16u;   // byte offset of this lane's k-chunk
#pragma unroll 1
  for (int ks = 0; ks < 4; ++ks) {
    uint kb = (uint)ks * 64u + kc;
    bf16x8 af = *(const bf16x8*)((const char*)As + arow * 256u + (kb ^ ((arow & 7u) << 4)));
    bf16x8 b0 = *(const bf16x8*)(wtf + (size_t)(((nt * 2 + 0) * 4 + ks) * 64 + lane) * 8);
    bf16x8 b1 = *(const bf16x8*)(wtf + (size_t)(((nt * 2 + 1) * 4 + ks) * 64 + lane) * 8);
    acc0 = __builtin_amdgcn_mfma_f32_16x16x32_bf16(af, b0, acc0, 0, 0, 0);
    acc1 = __builtin_amdgcn_mfma_f32_16x16x32_bf16(af, b1, acc1, 0, 0, 0);
  }
  // write C to its own padded buffer (As stays live for the residual)
  {
    uint nbase = (uint)nt << 5;
    uint rr = mrow + (((uint)(lane >> 4)) << 2);
    uint cc = nbase + (uint)(lane & 15);
#pragma unroll
    for (int j = 0; j < 4; ++j) {
      uint rj = rr + (uint)j;
      Cbuf[rj * 65u + cc]       = acc0[j];
      Cbuf[rj * 65u + cc + 16u] = acc1[j];
    }
  }
  __syncthreads();
  // epilogue: bias, graph pooling (sorted batch), residual (bf16 x from LDS), LN, ReLU
  float bv  = bvec[lane];
  float gv  = gamma[lane];
  float btv = beta[lane];
  int r0 = wl * 8;
  int gprev = -1; float pool = 0.f;
#pragma unroll
  for (int m = 0; m < 8; ++m) {
    uint r = (uint)(r0 + m);
    int node = node0 + r0 + m;
    float cval = Cbuf[r * 65u + (uint)lane];
    float tmp = cval + bv;
    int gi = batch[node];
    if (gi != gprev) {
      if (gprev >= 0) atomicAdd(&gacc[gprev * DD + lane], pool);
      pool = 0.f; gprev = gi;
    }
    pool += tmp;
    ushort xv16 = *(const ushort*)((const char*)As + r * 256u + (((uint)lane * 2u) ^ ((r & 7u) << 4)));
    float val = tmp + __uint_as_float((uint)xv16 << 16);
    float s = val;
    for (int off = 32; off; off >>= 1) s += __shfl_xor(s, off);
    float mu  = s * (1.f / 64.f);
    float dlt = val - mu;
    float ss  = dlt * dlt;
    for (int off = 32; off; off >>= 1) ss += __shfl_xor(ss, off);
    float rstd = rsqrtf(ss * (1.f / 64.f) + EPSV);
    float o = dlt * rstd * gv + btv;
    out[(size_t)node * DD + lane] = fmaxf(o, 0.f);
  }
  if (gprev >= 0) atomicAdd(&gacc[gprev * DD + lane], pool);
}

__global__ __launch_bounds__(256) void graph_k(const float* __restrict__ gacc, const float* __restrict__ gemb,
                                               const float* __restrict__ gamma, const float* __restrict__ beta,
                                               float* __restrict__ out) {
  int lane = threadIdx.x & 63;
  int w = blockIdx.x * 4 + (threadIdx.x >> 6);
  if (w >= N_GRAPHS) return;
  float v = gacc[w * DD + lane] + gemb[w * DD + lane];
  float gv = gamma[lane], btv = beta[lane];
#pragma unroll
  for (int it = 0; it < 2; ++it) {
    float s = v;
    for (int off = 32; off; off >>= 1) s += __shfl_xor(s, off);
    float mu  = s * (1.f / 64.f);
    float d   = v - mu;
    float ss  = d * d;
    for (int off = 32; off; off >>= 1) ss += __shfl_xor(ss, off);
    v = d * rsqrtf(ss * (1.f / 64.f) + EPSV) * gv + btv;
  }
  out[(size_t)N_NODES * DD + w * DD + lane] = v;
}

extern "C" void kernel_launch(void* const* d_in, const int* in_sizes, int n_in,
                              void* d_out, int out_size, void* d_ws, size_t ws_size,
                              hipStream_t stream) {
  const float* x      = (const float*)d_in[0];
  const int*   ei     = (const int*)d_in[1];
  const int*   batch  = (const int*)d_in[2];
  const float* gemb   = (const float*)d_in[3];
  const float* Wself  = (const float*)d_in[4];
  const float* Wneigh = (const float*)d_in[5];
  const float* bvec   = (const float*)d_in[6];
  const float* gamma  = (const float*)d_in[7];
  const float* beta   = (const float*)d_in[8];

  char* ws = (char*)d_ws;
  int*    cur  = (int*)(ws + O_CUR);
  int*    bkt  = (int*)(ws + O_BKT);
  float*  gacc = (float*)(ws + O_GACC);
  ushort* xb   = (ushort*)(ws + O_XB);
  ushort* wtf  = (ushort*)(ws + O_WTF);
  float*  outf = (float*)d_out;

  cast_k <<<N_NODES * DD / 4 / 256, 256, 0, stream>>>(x, xb, cur, gacc);
  scatP_k<<<NBLK, THRP, 0, stream>>>(ei, cur, bkt, Wself, Wneigh, wtf);
  aggM_k <<<NBUCK, 256, 0, stream>>>(xb, cur, bkt, wtf, bvec, gamma, beta,
                                     batch, gacc, outf);
  graph_k<<<N_GRAPHS / 4, 256, 0, stream>>>(gacc, gemb, gamma, beta, outf);
}

// Round 18
// 89.405 us; speedup vs baseline: 1.0465x; 1.0465x over previous
//
#include <hip/hip_runtime.h>

#define N_NODES  100000
#define N_EDGES  1600000
#define N_GRAPHS 128
#define DD       64
#define EPSV     1e-5f

#define BSH      5          // bucket = dst >> 5  (32 nodes per bucket)
#define BMASK    31
#define NBUCK    3125       // 100000/32 exactly
#define NBPAD    4096       // hist padded to 4*1024 for the block scan
#define CAPB     768        // max bucket entries used downstream (mean 512, 11 sigma)

#define THRP     1024       // scatter block threads
#define EPT      16         // edges per thread
#define BLKE     (THRP*EPT) // 16384
#define NBLK     ((N_EDGES + BLKE - 1) / BLKE)   // 98

// workspace byte offsets
#define O_ORD   200704u     // int[NBLK*BLKE]  block-private bucket-sorted edges (6.42MB)
#define O_DESC  6754304u    // int[NBLK*NBUCK] (start<<10)|cnt per (block,bucket) (1.23MB)
#define O_GACC  9801216u    // float[G*D]; bytes [9833984,9834496) = zero row (gather tail target)
#define O_XB    9834496u    // ushort[N_NODES*DD]  bf16 copy of x
#define O_WTF   22634496u   // ushort[1024*8]  B-operand in MFMA fragment layout (16 KB)
#define WS_NEED (O_WTF + 16384u)

typedef __attribute__((ext_vector_type(8))) short bf16x8;
typedef __attribute__((ext_vector_type(4))) float f32x4;
typedef __attribute__((ext_vector_type(2))) float f32x2;

__device__ __forceinline__ ushort bf16rne(float f) {
  uint u = __float_as_uint(f);
  return (ushort)((u + 0x7FFFu + ((u >> 16) & 1u)) >> 16);
}
__device__ __forceinline__ uint pk2(float lo, float hi) {
  return (uint)bf16rne(lo) | ((uint)bf16rne(hi) << 16);
}

// full-grid fp32->bf16 cast of x + zero-init of gacc and the 512B zero row
__global__ __launch_bounds__(256) void cast_k(const float* __restrict__ x, ushort* __restrict__ xb,
                                              float* __restrict__ gacc) {
  int i = blockIdx.x * 256 + threadIdx.x;      // grid 6250*256 = 1.6M = N_NODES*DD/4 exactly
  if (i < N_GRAPHS * DD) gacc[i] = 0.f;
  if (i < 128) gacc[N_GRAPHS * DD + i] = 0.f;  // zero row gap at ws+9833984 (= xb - 512)
  float4 v = ((const float4*)x)[i];
  uint4 u = *(const uint4*)&v;
  ushort4 o;
  o.x = (ushort)((u.x + 0x7FFFu + ((u.x >> 16) & 1)) >> 16);
  o.y = (ushort)((u.y + 0x7FFFu + ((u.y >> 16) & 1)) >> 16);
  o.z = (ushort)((u.z + 0x7FFFu + ((u.z >> 16) & 1)) >> 16);
  o.w = (ushort)((u.w + 0x7FFFu + ((u.w >> 16) & 1)) >> 16);
  ((ushort4*)xb)[i] = o;
}

// Per-block bucket sort with PRIVATE output regions — zero global atomics.
// Block writes ordered[blk*BLKE + rank] (rank = block-local bucket-sorted position,
// L2-local 64KB region) and desc[blk*NBUCK + b] = (start<<10)|cnt (coalesced).
// Block 0 also builds the MFMA B-operand image wtf.
__global__ __launch_bounds__(1024) void scatS_k(const int* __restrict__ ei,
                                                int* __restrict__ ordered,
                                                int* __restrict__ desc,
                                                const float* __restrict__ Wself,
                                                const float* __restrict__ Wneigh,
                                                ushort* __restrict__ wtf) {
  __shared__ int hist[NBPAD];
  __shared__ int cur2[NBPAD];
  __shared__ int wtot[16];
  int t = threadIdx.x;
  if (blockIdx.x == 0) {
    // fragment f=(nt,tile,ks,lane): 8 bf16 of WT[nt*32+tile*16+(lane&15)][ks*32+(lane>>4)*8+j]
    int lane = t & 63, ks = (t >> 6) & 3, tile = (t >> 8) & 1, nt = t >> 9;
    int brow = (nt << 5) + (tile << 4) + (lane & 15);
    int k0 = (ks << 5) + (((lane >> 4) & 3) << 3);
    uint4 o;
    uint p[4];
#pragma unroll
    for (int jj = 0; jj < 4; ++jj) {
      int k = k0 + jj * 2;
      float w0 = (k < 64)     ? Wself[k * DD + brow]       : Wneigh[(k - 64) * DD + brow];
      float w1 = (k + 1 < 64) ? Wself[(k + 1) * DD + brow] : Wneigh[(k - 63) * DD + brow];
      p[jj] = pk2(w0, w1);
    }
    o.x = p[0]; o.y = p[1]; o.z = p[2]; o.w = p[3];
    ((uint4*)wtf)[t] = o;
  }
  for (int i = t; i < NBPAD; i += THRP) hist[i] = 0;
  __syncthreads();
  int e0 = blockIdx.x * BLKE;
  int pk[EPT], bn[EPT];
#pragma unroll
  for (int j = 0; j < EPT; ++j) {
    int e = e0 + j * THRP + t;
    bn[j] = -1;
    if (e < N_EDGES) {
      int s = ei[e], d = ei[N_EDGES + e];
      bn[j] = d >> BSH;
      pk[j] = s | ((d & BMASK) << 17);
      atomicAdd(&hist[bn[j]], 1);
    }
  }
  __syncthreads();
  // block-wide exclusive scan over 4096 bins (thread t owns bins 4t..4t+3)
  int h0 = hist[4 * t], h1 = hist[4 * t + 1], h2 = hist[4 * t + 2], h3 = hist[4 * t + 3];
  int s = h0 + h1 + h2 + h3;
  int lane = t & 63, wv = t >> 6;
  int inc = s;
#pragma unroll
  for (int off = 1; off < 64; off <<= 1) {
    int u = __shfl_up(inc, off);
    if (lane >= off) inc += u;
  }
  if (lane == 63) wtot[wv] = inc;
  __syncthreads();
  if (t < 16) {
    int v = wtot[t];
    int iv = v;
#pragma unroll
    for (int off = 1; off < 16; off <<= 1) {
      int u = __shfl_up(iv, off);
      if (t >= off) iv += u;
    }
    wtot[t] = iv - v;   // exclusive wave base
  }
  __syncthreads();
  int base = wtot[wv] + (inc - s);
  cur2[4 * t]     = base;
  cur2[4 * t + 1] = base + h0;
  cur2[4 * t + 2] = base + h0 + h1;
  cur2[4 * t + 3] = base + h0 + h1 + h2;
  // descriptors (own bins -> no barrier needed before; coalesced global write)
  {
    int dbase = blockIdx.x * NBUCK;
#pragma unroll
    for (int i = 0; i < 4; ++i) {
      int bb = 4 * t + i;
      if (bb < NBUCK) desc[dbase + bb] = (cur2[bb] << 10) | hist[bb];
    }
  }
  __syncthreads();
  // ranked stores into the block's PRIVATE 64KB region (L2-local)
  int obase = blockIdx.x * BLKE;
#pragma unroll
  for (int j = 0; j < EPT; ++j) {
    if (bn[j] >= 0) {
      int sp = atomicAdd(&cur2[bn[j]], 1);
      ordered[obase + sp] = pk[j];
    }
  }
}

// FUSED per-bucket kernel: descriptor-driven slab assembly -> counting-sort ->
// pull-based mean (R15 gather) -> MFMA combine (register B) -> epilogue.
__global__ __launch_bounds__(256, 8) void aggM_k(const ushort* __restrict__ xb,
                                                 const int* __restrict__ ordered,
                                                 const int* __restrict__ desc,
                                                 const ushort* __restrict__ wtf,
                                                 const float* __restrict__ bvec,
                                                 const float* __restrict__ gamma,
                                                 const float* __restrict__ beta,
                                                 const int* __restrict__ batch,
                                                 float* __restrict__ gacc,
                                                 float* __restrict__ out) {
  __shared__ short As[32 * 128];    // 8KB: A=[xb|h] bf16 swizzled; LIVE through epilogue
  __shared__ float Cbuf[32 * 65];   // 8.3KB: slab (pre-MFMA) THEN MFMA C (post-gather)
  __shared__ int sorted[CAPB + 16]; // byte offsets (idx*128+512), +16 pad for tail reads
  __shared__ int hist[32], startc[32], curl[32];
  __shared__ int wsum2[2];
  __shared__ int nTot_s;
  int* slabL = (int*)Cbuf;          // 2080-int capacity, used only before MFMA
  int t = threadIdx.x;
  int b = blockIdx.x;
  int node0 = b << BSH;
  if (t < 32) hist[t] = 0;
  // stage A x-part (k=0..63): contiguous 4KB read of this bucket's xb rows
  {
    uint4 v = ((const uint4*)(xb + (size_t)node0 * DD))[t];   // t = r*8 + c
    uint r = (uint)t >> 3, c = (uint)t & 7;
    *(uint4*)((char*)As + r * 256u + ((c * 16u) ^ ((r & 7u) << 4))) = v;
  }
  // descriptor read (one per scatter block) + 128-thread scan of counts
  int dsc = (t < NBLK) ? desc[t * NBUCK + b] : 0;
  int c   = dsc & 1023;
  int st  = dsc >> 10;
  int inc = c;
  if (t < 128) {
    int lane = t & 63;
#pragma unroll
    for (int off = 1; off < 64; off <<= 1) {
      int u = __shfl_up(inc, off);
      if (lane >= off) inc += u;
    }
    if (lane == 63) wsum2[t >> 6] = inc;
  }
  __syncthreads();
  int pos = 0;
  if (t < 128) pos = ((t >> 6) ? wsum2[0] : 0) + inc - c;
  if (t == 0) nTot_s = wsum2[0] + wsum2[1];
  // copy this block's run into the LDS slab (runs avg ~5 entries)
  if (t < NBLK) {
    int lim = CAPB - pos;
    int cc = c < lim ? c : (lim > 0 ? lim : 0);
    const int* srcp = ordered + (size_t)t * BLKE + st;
    for (int i = 0; i < cc; ++i) slabL[pos + i] = srcp[i];
  }
  __syncthreads();
  int n = nTot_s;
  if (n > CAPB) n = CAPB;
  int w0 = -1, w1 = -1, w2 = -1;
  if (t < n)       { w0 = slabL[t];       atomicAdd(&hist[w0 >> 17], 1); }
  if (t + 256 < n) { w1 = slabL[t + 256]; atomicAdd(&hist[w1 >> 17], 1); }
  if (t + 512 < n) { w2 = slabL[t + 512]; atomicAdd(&hist[w2 >> 17], 1); }
  __syncthreads();
  // exclusive scan of 32 bins: wave-0 shuffle scan, ONE barrier
  if (t < 32) {
    int h = hist[t];
    int v = h;
#pragma unroll
    for (int off = 1; off < 32; off <<= 1) {
      int u = __shfl_up(v, off);
      if (t >= off) v += u;
    }
    startc[t] = v - h;
    curl[t]   = v - h;
  }
  __syncthreads();
  if (w0 >= 0) { int p = atomicAdd(&curl[w0 >> 17], 1); sorted[p] = ((w0 & 0x1FFFF) << 7) + 512; }
  if (w1 >= 0) { int p = atomicAdd(&curl[w1 >> 17], 1); sorted[p] = ((w1 & 0x1FFFF) << 7) + 512; }
  if (w2 >= 0) { int p = atomicAdd(&curl[w2 >> 17], 1); sorted[p] = ((w2 & 0x1FFFF) << 7) + 512; }
  __syncthreads();
  int wl   = __builtin_amdgcn_readfirstlane(t >> 6);
  int lane = t & 63;
  int g    = lane >> 4;     // edge-group 0..3
  int sub  = lane & 15;     // dim group: dims [sub*4, sub*4+4)
  const char* zb = (const char*)xb - 512;   // base: +0 hits the zero row, +sorted hits xb
  uint subb = (uint)sub * 8u;
  // pull aggregation: 4 edges per instruction x 4 loads in flight; mean -> A k=64..127
  for (int r = wl; r < 32; r += 4) {
    int s0 = startc[r], dg = hist[r];
    f32x2 A01 = {0.f, 0.f}, A23 = {0.f, 0.f};
    for (int j = 0; j < dg; j += 16) {
      int e0 = j + g, e1 = j + 4 + g, e2 = j + 8 + g, e3 = j + 12 + g;
      uint o0 = (uint)sorted[s0 + e0]; if (e0 >= dg) o0 = 0u;   // tail -> zero row
      uint o1 = (uint)sorted[s0 + e1]; if (e1 >= dg) o1 = 0u;
      uint o2 = (uint)sorted[s0 + e2]; if (e2 >= dg) o2 = 0u;
      uint o3 = (uint)sorted[s0 + e3]; if (e3 >= dg) o3 = 0u;
      uint2 u0 = *(const uint2*)(zb + o0 + subb);               // 4 gathers in flight
      uint2 u1 = *(const uint2*)(zb + o1 + subb);
      uint2 u2 = *(const uint2*)(zb + o2 + subb);
      uint2 u3 = *(const uint2*)(zb + o3 + subb);
      f32x2 v0, v1, v2, v3, y0, y1, y2, y3;
      v0.x = __uint_as_float(u0.x << 16); v0.y = __uint_as_float(u0.x & 0xFFFF0000u);
      v1.x = __uint_as_float(u1.x << 16); v1.y = __uint_as_float(u1.x & 0xFFFF0000u);
      v2.x = __uint_as_float(u2.x << 16); v2.y = __uint_as_float(u2.x & 0xFFFF0000u);
      v3.x = __uint_as_float(u3.x << 16); v3.y = __uint_as_float(u3.x & 0xFFFF0000u);
      y0.x = __uint_as_float(u0.y << 16); y0.y = __uint_as_float(u0.y & 0xFFFF0000u);
      y1.x = __uint_as_float(u1.y << 16); y1.y = __uint_as_float(u1.y & 0xFFFF0000u);
      y2.x = __uint_as_float(u2.y << 16); y2.y = __uint_as_float(u2.y & 0xFFFF0000u);
      y3.x = __uint_as_float(u3.y << 16); y3.y = __uint_as_float(u3.y & 0xFFFF0000u);
      A01 += (v0 + v1) + (v2 + v3);
      A23 += (y0 + y1) + (y2 + y3);
    }
    float a0 = A01.x, a1 = A01.y, a2 = A23.x, a3 = A23.y;
    // merge the 4 edge-groups: butterfly over lane bits 4,5
#pragma unroll
    for (int off = 16; off <= 32; off <<= 1) {
      a0 += __shfl_xor(a0, off);
      a1 += __shfl_xor(a1, off);
      a2 += __shfl_xor(a2, off);
      a3 += __shfl_xor(a3, off);
    }
    if (g == 0) {
      float inv = 1.f / fmaxf((float)dg, 1.f);
      uint2 pw;
      pw.x = pk2(a0 * inv, a1 * inv);
      pw.y = pk2(a2 * inv, a3 * inv);
      uint rr = (uint)r;
      *(uint2*)((char*)As + rr * 256u + ((128u + (uint)sub * 8u) ^ ((rr & 7u) << 4))) = pw;
    }
  }
  __syncthreads();    // gather done; slabL dead -> Cbuf reuse is safe after MFMA writes
  // MFMA combine: wave -> (mrow, n-tile pair); B fragments streamed from global (L2-hot)
  f32x4 acc0 = {0.f, 0.f, 0.f, 0.f}, acc1 = {0.f, 0.f, 0.f, 0.f};
  uint mrow  = (uint)(wl >> 1) << 4;   // 0 / 16
  int  nt    = wl & 1;
  uint arow  = mrow + (uint)(lane & 15);
  uint kc    = ((uint)(lane >> 4)) * 16u;   // byte offset of this lane's k-chunk
#pragma unroll 1
  for (int ks = 0; ks < 4; ++ks) {
    uint kb = (uint)ks * 64u + kc;
    bf16x8 af = *(const bf16x8*)((const char*)As + arow * 256u + (kb ^ ((arow & 7u) << 4)));
    bf16x8 b0 = *(const bf16x8*)(wtf + (size_t)(((nt * 2 + 0) * 4 + ks) * 64 + lane) * 8);
    bf16x8 b1 = *(const bf16x8*)(wtf + (size_t)(((nt * 2 + 1) * 4 + ks) * 64 + lane) * 8);
    acc0 = __builtin_amdgcn_mfma_f32_16x16x32_bf16(af, b0, acc0, 0, 0, 0);
    acc1 = __builtin_amdgcn_mfma_f32_16x16x32_bf16(af, b1, acc1, 0, 0, 0);
  }
  // write C to the padded buffer (As stays live for the residual)
  {
    uint nbase = (uint)nt << 5;
    uint rr = mrow + (((uint)(lane >> 4)) << 2);
    uint cc = nbase + (uint)(lane & 15);
#pragma unroll
    for (int j = 0; j < 4; ++j) {
      uint rj = rr + (uint)j;
      Cbuf[rj * 65u + cc]       = acc0[j];
      Cbuf[rj * 65u + cc + 16u] = acc1[j];
    }
  }
  __syncthreads();
  // epilogue: bias, graph pooling (sorted batch), residual (bf16 x from LDS), LN, ReLU
  float bv  = bvec[lane];
  float gv  = gamma[lane];
  float btv = beta[lane];
  int r0 = wl * 8;
  int gprev = -1; float pool = 0.f;
#pragma unroll
  for (int m = 0; m < 8; ++m) {
    uint r = (uint)(r0 + m);
    int node = node0 + r0 + m;
    float cval = Cbuf[r * 65u + (uint)lane];
    float tmp = cval + bv;
    int gi = batch[node];
    if (gi != gprev) {
      if (gprev >= 0) atomicAdd(&gacc[gprev * DD + lane], pool);
      pool = 0.f; gprev = gi;
    }
    pool += tmp;
    ushort xv16 = *(const ushort*)((const char*)As + r * 256u + (((uint)lane * 2u) ^ ((r & 7u) << 4)));
    float val = tmp + __uint_as_float((uint)xv16 << 16);
    float s = val;
    for (int off = 32; off; off >>= 1) s += __shfl_xor(s, off);
    float mu  = s * (1.f / 64.f);
    float dlt = val - mu;
    float ss  = dlt * dlt;
    for (int off = 32; off; off >>= 1) ss += __shfl_xor(ss, off);
    float rstd = rsqrtf(ss * (1.f / 64.f) + EPSV);
    float o = dlt * rstd * gv + btv;
    out[(size_t)node * DD + lane] = fmaxf(o, 0.f);
  }
  if (gprev >= 0) atomicAdd(&gacc[gprev * DD + lane], pool);
}

__global__ __launch_bounds__(256) void graph_k(const float* __restrict__ gacc, const float* __restrict__ gemb,
                                               const float* __restrict__ gamma, const float* __restrict__ beta,
                                               float* __restrict__ out) {
  int lane = threadIdx.x & 63;
  int w = blockIdx.x * 4 + (threadIdx.x >> 6);
  if (w >= N_GRAPHS) return;
  float v = gacc[w * DD + lane] + gemb[w * DD + lane];
  float gv = gamma[lane], btv = beta[lane];
#pragma unroll
  for (int it = 0; it < 2; ++it) {
    float s = v;
    for (int off = 32; off; off >>= 1) s += __shfl_xor(s, off);
    float mu  = s * (1.f / 64.f);
    float d   = v - mu;
    float ss  = d * d;
    for (int off = 32; off; off >>= 1) ss += __shfl_xor(ss, off);
    v = d * rsqrtf(ss * (1.f / 64.f) + EPSV) * gv + btv;
  }
  out[(size_t)N_NODES * DD + w * DD + lane] = v;
}

extern "C" void kernel_launch(void* const* d_in, const int* in_sizes, int n_in,
                              void* d_out, int out_size, void* d_ws, size_t ws_size,
                              hipStream_t stream) {
  const float* x      = (const float*)d_in[0];
  const int*   ei     = (const int*)d_in[1];
  const int*   batch  = (const int*)d_in[2];
  const float* gemb   = (const float*)d_in[3];
  const float* Wself  = (const float*)d_in[4];
  const float* Wneigh = (const float*)d_in[5];
  const float* bvec   = (const float*)d_in[6];
  const float* gamma  = (const float*)d_in[7];
  const float* beta   = (const float*)d_in[8];

  char* ws = (char*)d_ws;
  int*    ordered = (int*)(ws + O_ORD);
  int*    desc    = (int*)(ws + O_DESC);
  float*  gacc    = (float*)(ws + O_GACC);
  ushort* xb      = (ushort*)(ws + O_XB);
  ushort* wtf     = (ushort*)(ws + O_WTF);
  float*  outf    = (float*)d_out;

  cast_k <<<N_NODES * DD / 4 / 256, 256, 0, stream>>>(x, xb, gacc);
  scatS_k<<<NBLK, THRP, 0, stream>>>(ei, ordered, desc, Wself, Wneigh, wtf);
  aggM_k <<<NBUCK, 256, 0, stream>>>(xb, ordered, desc, wtf, bvec, gamma, beta,
                                     batch, gacc, outf);
  graph_k<<<N_GRAPHS / 4, 256, 0, stream>>>(gacc, gemb, gamma, beta, outf);
}

// Round 19
// 87.449 us; speedup vs baseline: 1.0699x; 1.0224x over previous
//
#include <hip/hip_runtime.h>

#define N_NODES  100000
#define N_EDGES  1600000
#define N_GRAPHS 128
#define DD       64
#define EPSV     1e-5f

#define BSH      5          // bucket = dst >> 5  (32 nodes per bucket)
#define BMASK    31
#define NBUCK    3125       // 100000/32 exactly
#define NBPAD    4096       // hist padded to 4*1024 for the block scan
#define CAPB     768        // max bucket entries used downstream (mean 512, 11 sigma)

#define THRP     1024       // scatter block threads
#define EPT      16         // edges per thread
#define BLKE     (THRP*EPT) // 16384
#define NBLK     ((N_EDGES + BLKE - 1) / BLKE)   // 98

// workspace byte offsets
#define O_ORD   200704u     // int[NBLK*BLKE]  block-private bucket-sorted edges (6.42MB)
#define O_DESC  6754304u    // int[NBUCK*NBLK] TRANSPOSED: (start<<10)|cnt, contiguous per bucket
#define O_GACC  9801216u    // float[G*D]; bytes [9833984,9834496) = zero row (gather tail target)
#define O_XB    9834496u    // ushort[N_NODES*DD]  bf16 copy of x
#define O_WTF   22634496u   // ushort[1024*8]  B-operand in MFMA fragment layout (16 KB)
#define WS_NEED (O_WTF + 16384u)

typedef __attribute__((ext_vector_type(8))) short bf16x8;
typedef __attribute__((ext_vector_type(4))) float f32x4;
typedef __attribute__((ext_vector_type(2))) float f32x2;

__device__ __forceinline__ ushort bf16rne(float f) {
  uint u = __float_as_uint(f);
  return (ushort)((u + 0x7FFFu + ((u >> 16) & 1u)) >> 16);
}
__device__ __forceinline__ uint pk2(float lo, float hi) {
  return (uint)bf16rne(lo) | ((uint)bf16rne(hi) << 16);
}

// full-grid fp32->bf16 cast of x + zero-init of gacc and the 512B zero row
__global__ __launch_bounds__(256) void cast_k(const float* __restrict__ x, ushort* __restrict__ xb,
                                              float* __restrict__ gacc) {
  int i = blockIdx.x * 256 + threadIdx.x;      // grid 6250*256 = 1.6M = N_NODES*DD/4 exactly
  if (i < N_GRAPHS * DD) gacc[i] = 0.f;
  if (i < 128) gacc[N_GRAPHS * DD + i] = 0.f;  // zero row gap at ws+9833984 (= xb - 512)
  float4 v = ((const float4*)x)[i];
  uint4 u = *(const uint4*)&v;
  ushort4 o;
  o.x = (ushort)((u.x + 0x7FFFu + ((u.x >> 16) & 1)) >> 16);
  o.y = (ushort)((u.y + 0x7FFFu + ((u.y >> 16) & 1)) >> 16);
  o.z = (ushort)((u.z + 0x7FFFu + ((u.z >> 16) & 1)) >> 16);
  o.w = (ushort)((u.w + 0x7FFFu + ((u.w >> 16) & 1)) >> 16);
  ((ushort4*)xb)[i] = o;
}

// Per-block bucket sort with PRIVATE output regions — zero global atomics.
// ordered[blk*BLKE + rank] (L2-local 64KB region); desc TRANSPOSED:
// desc[b*NBLK + blk] = (start<<10)|cnt so aggM's read is one coalesced row.
// Block 0 also builds the MFMA B-operand image wtf.
__global__ __launch_bounds__(1024) void scatS_k(const int* __restrict__ ei,
                                                int* __restrict__ ordered,
                                                int* __restrict__ desc,
                                                const float* __restrict__ Wself,
                                                const float* __restrict__ Wneigh,
                                                ushort* __restrict__ wtf) {
  __shared__ int hist[NBPAD];
  __shared__ int cur2[NBPAD];
  __shared__ int wtot[16];
  int t = threadIdx.x;
  if (blockIdx.x == 0) {
    // fragment f=(nt,tile,ks,lane): 8 bf16 of WT[nt*32+tile*16+(lane&15)][ks*32+(lane>>4)*8+j]
    int lane = t & 63, ks = (t >> 6) & 3, tile = (t >> 8) & 1, nt = t >> 9;
    int brow = (nt << 5) + (tile << 4) + (lane & 15);
    int k0 = (ks << 5) + (((lane >> 4) & 3) << 3);
    uint4 o;
    uint p[4];
#pragma unroll
    for (int jj = 0; jj < 4; ++jj) {
      int k = k0 + jj * 2;
      float w0 = (k < 64)     ? Wself[k * DD + brow]       : Wneigh[(k - 64) * DD + brow];
      float w1 = (k + 1 < 64) ? Wself[(k + 1) * DD + brow] : Wneigh[(k - 63) * DD + brow];
      p[jj] = pk2(w0, w1);
    }
    o.x = p[0]; o.y = p[1]; o.z = p[2]; o.w = p[3];
    ((uint4*)wtf)[t] = o;
  }
  for (int i = t; i < NBPAD; i += THRP) hist[i] = 0;
  __syncthreads();
  int e0 = blockIdx.x * BLKE;
  int pk[EPT], bn[EPT];
#pragma unroll
  for (int j = 0; j < EPT; ++j) {
    int e = e0 + j * THRP + t;
    bn[j] = -1;
    if (e < N_EDGES) {
      int s = ei[e], d = ei[N_EDGES + e];
      bn[j] = d >> BSH;
      pk[j] = s | ((d & BMASK) << 17);
      atomicAdd(&hist[bn[j]], 1);
    }
  }
  __syncthreads();
  // block-wide exclusive scan over 4096 bins (thread t owns bins 4t..4t+3)
  int h0 = hist[4 * t], h1 = hist[4 * t + 1], h2 = hist[4 * t + 2], h3 = hist[4 * t + 3];
  int s = h0 + h1 + h2 + h3;
  int lane = t & 63, wv = t >> 6;
  int inc = s;
#pragma unroll
  for (int off = 1; off < 64; off <<= 1) {
    int u = __shfl_up(inc, off);
    if (lane >= off) inc += u;
  }
  if (lane == 63) wtot[wv] = inc;
  __syncthreads();
  if (t < 16) {
    int v = wtot[t];
    int iv = v;
#pragma unroll
    for (int off = 1; off < 16; off <<= 1) {
      int u = __shfl_up(iv, off);
      if (t >= off) iv += u;
    }
    wtot[t] = iv - v;   // exclusive wave base
  }
  __syncthreads();
  int base = wtot[wv] + (inc - s);
  cur2[4 * t]     = base;
  cur2[4 * t + 1] = base + h0;
  cur2[4 * t + 2] = base + h0 + h1;
  cur2[4 * t + 3] = base + h0 + h1 + h2;
  // descriptors, transposed layout (own bins -> no barrier needed before)
  {
#pragma unroll
    for (int i = 0; i < 4; ++i) {
      int bb = 4 * t + i;
      if (bb < NBUCK) desc[bb * NBLK + blockIdx.x] = (cur2[bb] << 10) | hist[bb];
    }
  }
  __syncthreads();
  // ranked stores into the block's PRIVATE 64KB region (L2-local)
  int obase = blockIdx.x * BLKE;
#pragma unroll
  for (int j = 0; j < EPT; ++j) {
    if (bn[j] >= 0) {
      int sp = atomicAdd(&cur2[bn[j]], 1);
      ordered[obase + sp] = pk[j];
    }
  }
}

// FUSED per-bucket kernel: coalesced descriptor row -> run-prefix scan -> per-entry
// binary-search loads from ordered -> counting-sort -> pull-based mean -> MFMA -> epilogue.
__global__ __launch_bounds__(256, 8) void aggM_k(const ushort* __restrict__ xb,
                                                 const int* __restrict__ ordered,
                                                 const int* __restrict__ desc,
                                                 const ushort* __restrict__ wtf,
                                                 const float* __restrict__ bvec,
                                                 const float* __restrict__ gamma,
                                                 const float* __restrict__ beta,
                                                 const int* __restrict__ batch,
                                                 float* __restrict__ gacc,
                                                 float* __restrict__ out) {
  __shared__ short As[32 * 128];    // 8KB: A=[xb|h] bf16 swizzled; LIVE through epilogue
  __shared__ float Cbuf[32 * 65];   // 8.3KB: MFMA C (padded rows)
  __shared__ int sorted[CAPB + 16]; // [0..127]=posA, [128..255]=stA during assembly; then ranked slots
  __shared__ int hist[32], startc[32], curl[32];
  __shared__ int wsum2[2];
  __shared__ int nTot_s;
  int* posA = sorted;               // run start positions (prefix), pad INT_MAX
  int* stA  = sorted + 128;         // run source index in ordered
  int t = threadIdx.x;
  int b = blockIdx.x;
  int node0 = b << BSH;
  if (t < 32) hist[t] = 0;
  // stage A x-part (k=0..63): contiguous 4KB read of this bucket's xb rows
  {
    uint4 v = ((const uint4*)(xb + (size_t)node0 * DD))[t];   // t = r*8 + c
    uint r = (uint)t >> 3, c = (uint)t & 7;
    *(uint4*)((char*)As + r * 256u + ((c * 16u) ^ ((r & 7u) << 4))) = v;
  }
  // coalesced descriptor row + 128-thread scan of counts
  int dsc = (t < NBLK) ? desc[b * NBLK + t] : 0;
  int c   = dsc & 1023;
  int st  = dsc >> 10;
  int inc = c;
  if (t < 128) {
    int lane = t & 63;
#pragma unroll
    for (int off = 1; off < 64; off <<= 1) {
      int u = __shfl_up(inc, off);
      if (lane >= off) inc += u;
    }
    if (lane == 63) wsum2[t >> 6] = inc;
  }
  __syncthreads();
  if (t < 128) {
    int pos = ((t >> 6) ? wsum2[0] : 0) + inc - c;
    posA[t] = (t < NBLK) ? pos : 0x7FFFFFFF;
    stA[t]  = t * BLKE + st;
  }
  if (t == 0) nTot_s = wsum2[0] + wsum2[1];
  __syncthreads();
  int n = nTot_s;
  if (n > CAPB) n = CAPB;
  // per-entry loads: branchless binary search for the containing run, direct global load
  auto bs_load = [&](int i) -> int {
    int lo = 0;
#pragma unroll
    for (int stp = 64; stp; stp >>= 1) {
      int cnd = lo + stp;
      lo = (posA[cnd] <= i) ? cnd : lo;
    }
    return ordered[stA[lo] + (i - posA[lo])];
  };
  int w0 = -1, w1 = -1, w2 = -1;
  if (t < n)       { w0 = bs_load(t);       atomicAdd(&hist[w0 >> 17], 1); }
  if (t + 256 < n) { w1 = bs_load(t + 256); atomicAdd(&hist[w1 >> 17], 1); }
  if (t + 512 < n) { w2 = bs_load(t + 512); atomicAdd(&hist[w2 >> 17], 1); }
  __syncthreads();
  // exclusive scan of 32 bins: wave-0 shuffle scan, ONE barrier
  if (t < 32) {
    int h = hist[t];
    int v = h;
#pragma unroll
    for (int off = 1; off < 32; off <<= 1) {
      int u = __shfl_up(v, off);
      if (t >= off) v += u;
    }
    startc[t] = v - h;
    curl[t]   = v - h;
  }
  __syncthreads();
  if (w0 >= 0) { int p = atomicAdd(&curl[w0 >> 17], 1); sorted[p] = ((w0 & 0x1FFFF) << 7) + 512; }
  if (w1 >= 0) { int p = atomicAdd(&curl[w1 >> 17], 1); sorted[p] = ((w1 & 0x1FFFF) << 7) + 512; }
  if (w2 >= 0) { int p = atomicAdd(&curl[w2 >> 17], 1); sorted[p] = ((w2 & 0x1FFFF) << 7) + 512; }
  __syncthreads();
  int wl   = __builtin_amdgcn_readfirstlane(t >> 6);
  int lane = t & 63;
  int g    = lane >> 4;     // edge-group 0..3
  int sub  = lane & 15;     // dim group: dims [sub*4, sub*4+4)
  const char* zb = (const char*)xb - 512;   // base: +0 hits the zero row, +sorted hits xb
  uint subb = (uint)sub * 8u;
  // pull aggregation: 4 edges per instruction x 4 loads in flight; mean -> A k=64..127
  for (int r = wl; r < 32; r += 4) {
    int s0 = startc[r], dg = hist[r];
    f32x2 A01 = {0.f, 0.f}, A23 = {0.f, 0.f};
    for (int j = 0; j < dg; j += 16) {
      int e0 = j + g, e1 = j + 4 + g, e2 = j + 8 + g, e3 = j + 12 + g;
      uint o0 = (uint)sorted[s0 + e0]; if (e0 >= dg) o0 = 0u;   // tail -> zero row
      uint o1 = (uint)sorted[s0 + e1]; if (e1 >= dg) o1 = 0u;
      uint o2 = (uint)sorted[s0 + e2]; if (e2 >= dg) o2 = 0u;
      uint o3 = (uint)sorted[s0 + e3]; if (e3 >= dg) o3 = 0u;
      uint2 u0 = *(const uint2*)(zb + o0 + subb);               // 4 gathers in flight
      uint2 u1 = *(const uint2*)(zb + o1 + subb);
      uint2 u2 = *(const uint2*)(zb + o2 + subb);
      uint2 u3 = *(const uint2*)(zb + o3 + subb);
      f32x2 v0, v1, v2, v3, y0, y1, y2, y3;
      v0.x = __uint_as_float(u0.x << 16); v0.y = __uint_as_float(u0.x & 0xFFFF0000u);
      v1.x = __uint_as_float(u1.x << 16); v1.y = __uint_as_float(u1.x & 0xFFFF0000u);
      v2.x = __uint_as_float(u2.x << 16); v2.y = __uint_as_float(u2.x & 0xFFFF0000u);
      v3.x = __uint_as_float(u3.x << 16); v3.y = __uint_as_float(u3.x & 0xFFFF0000u);
      y0.x = __uint_as_float(u0.y << 16); y0.y = __uint_as_float(u0.y & 0xFFFF0000u);
      y1.x = __uint_as_float(u1.y << 16); y1.y = __uint_as_float(u1.y & 0xFFFF0000u);
      y2.x = __uint_as_float(u2.y << 16); y2.y = __uint_as_float(u2.y & 0xFFFF0000u);
      y3.x = __uint_as_float(u3.y << 16); y3.y = __uint_as_float(u3.y & 0xFFFF0000u);
      A01 += (v0 + v1) + (v2 + v3);
      A23 += (y0 + y1) + (y2 + y3);
    }
    float a0 = A01.x, a1 = A01.y, a2 = A23.x, a3 = A23.y;
    // merge the 4 edge-groups: butterfly over lane bits 4,5
#pragma unroll
    for (int off = 16; off <= 32; off <<= 1) {
      a0 += __shfl_xor(a0, off);
      a1 += __shfl_xor(a1, off);
      a2 += __shfl_xor(a2, off);
      a3 += __shfl_xor(a3, off);
    }
    if (g == 0) {
      float inv = 1.f / fmaxf((float)dg, 1.f);
      uint2 pw;
      pw.x = pk2(a0 * inv, a1 * inv);
      pw.y = pk2(a2 * inv, a3 * inv);
      uint rr = (uint)r;
      *(uint2*)((char*)As + rr * 256u + ((128u + (uint)sub * 8u) ^ ((rr & 7u) << 4))) = pw;
    }
  }
  __syncthreads();
  // MFMA combine: wave -> (mrow, n-tile pair); B fragments streamed from global (L2-hot)
  f32x4 acc0 = {0.f, 0.f, 0.f, 0.f}, acc1 = {0.f, 0.f, 0.f, 0.f};
  uint mrow  = (uint)(wl >> 1) << 4;   // 0 / 16
  int  nt    = wl & 1;
  uint arow  = mrow + (uint)(lane & 15);
  uint kc    = ((uint)(lane >> 4)) * 16u;   // byte offset of this lane's k-chunk
#pragma unroll 1
  for (int ks = 0; ks < 4; ++ks) {
    uint kb = (uint)ks * 64u + kc;
    bf16x8 af = *(const bf16x8*)((const char*)As + arow * 256u + (kb ^ ((arow & 7u) << 4)));
    bf16x8 b0 = *(const bf16x8*)(wtf + (size_t)(((nt * 2 + 0) * 4 + ks) * 64 + lane) * 8);
    bf16x8 b1 = *(const bf16x8*)(wtf + (size_t)(((nt * 2 + 1) * 4 + ks) * 64 + lane) * 8);
    acc0 = __builtin_amdgcn_mfma_f32_16x16x32_bf16(af, b0, acc0, 0, 0, 0);
    acc1 = __builtin_amdgcn_mfma_f32_16x16x32_bf16(af, b1, acc1, 0, 0, 0);
  }
  // write C to the padded buffer (As stays live for the residual)
  {
    uint nbase = (uint)nt << 5;
    uint rr = mrow + (((uint)(lane >> 4)) << 2);
    uint cc = nbase + (uint)(lane & 15);
#pragma unroll
    for (int j = 0; j < 4; ++j) {
      uint rj = rr + (uint)j;
      Cbuf[rj * 65u + cc]       = acc0[j];
      Cbuf[rj * 65u + cc + 16u] = acc1[j];
    }
  }
  __syncthreads();
  // epilogue: bias, graph pooling (sorted batch), residual (bf16 x from LDS), LN, ReLU
  float bv  = bvec[lane];
  float gv  = gamma[lane];
  float btv = beta[lane];
  int r0 = wl * 8;
  int gprev = -1; float pool = 0.f;
#pragma unroll
  for (int m = 0; m < 8; ++m) {
    uint r = (uint)(r0 + m);
    int node = node0 + r0 + m;
    float cval = Cbuf[r * 65u + (uint)lane];
    float tmp = cval + bv;
    int gi = batch[node];
    if (gi != gprev) {
      if (gprev >= 0) atomicAdd(&gacc[gprev * DD + lane], pool);
      pool = 0.f; gprev = gi;
    }
    pool += tmp;
    ushort xv16 = *(const ushort*)((const char*)As + r * 256u + (((uint)lane * 2u) ^ ((r & 7u) << 4)));
    float val = tmp + __uint_as_float((uint)xv16 << 16);
    float s = val;
    for (int off = 32; off; off >>= 1) s += __shfl_xor(s, off);
    float mu  = s * (1.f / 64.f);
    float dlt = val - mu;
    float ss  = dlt * dlt;
    for (int off = 32; off; off >>= 1) ss += __shfl_xor(ss, off);
    float rstd = rsqrtf(ss * (1.f / 64.f) + EPSV);
    float o = dlt * rstd * gv + btv;
    out[(size_t)node * DD + lane] = fmaxf(o, 0.f);
  }
  if (gprev >= 0) atomicAdd(&gacc[gprev * DD + lane], pool);
}

__global__ __launch_bounds__(256) void graph_k(const float* __restrict__ gacc, const float* __restrict__ gemb,
                                               const float* __restrict__ gamma, const float* __restrict__ beta,
                                               float* __restrict__ out) {
  int lane = threadIdx.x & 63;
  int w = blockIdx.x * 4 + (threadIdx.x >> 6);
  if (w >= N_GRAPHS) return;
  float v = gacc[w * DD + lane] + gemb[w * DD + lane];
  float gv = gamma[lane], btv = beta[lane];
#pragma unroll
  for (int it = 0; it < 2; ++it) {
    float s = v;
    for (int off = 32; off; off >>= 1) s += __shfl_xor(s, off);
    float mu  = s * (1.f / 64.f);
    float d   = v - mu;
    float ss  = d * d;
    for (int off = 32; off; off >>= 1) ss += __shfl_xor(ss, off);
    v = d * rsqrtf(ss * (1.f / 64.f) + EPSV) * gv + btv;
  }
  out[(size_t)N_NODES * DD + w * DD + lane] = v;
}

extern "C" void kernel_launch(void* const* d_in, const int* in_sizes, int n_in,
                              void* d_out, int out_size, void* d_ws, size_t ws_size,
                              hipStream_t stream) {
  const float* x      = (const float*)d_in[0];
  const int*   ei     = (const int*)d_in[1];
  const int*   batch  = (const int*)d_in[2];
  const float* gemb   = (const float*)d_in[3];
  const float* Wself  = (const float*)d_in[4];
  const float* Wneigh = (const float*)d_in[5];
  const float* bvec   = (const float*)d_in[6];
  const float* gamma  = (const float*)d_in[7];
  const float* beta   = (const float*)d_in[8];

  char* ws = (char*)d_ws;
  int*    ordered = (int*)(ws + O_ORD);
  int*    desc    = (int*)(ws + O_DESC);
  float*  gacc    = (float*)(ws + O_GACC);
  ushort* xb      = (ushort*)(ws + O_XB);
  ushort* wtf     = (ushort*)(ws + O_WTF);
  float*  outf    = (float*)d_out;

  cast_k <<<N_NODES * DD / 4 / 256, 256, 0, stream>>>(x, xb, gacc);
  scatS_k<<<NBLK, THRP, 0, stream>>>(ei, ordered, desc, Wself, Wneigh, wtf);
  aggM_k <<<NBUCK, 256, 0, stream>>>(xb, ordered, desc, wtf, bvec, gamma, beta,
                                     batch, gacc, outf);
  graph_k<<<N_GRAPHS / 4, 256, 0, stream>>>(gacc, gemb, gamma, beta, outf);
}

// Round 20
// 85.277 us; speedup vs baseline: 1.0972x; 1.0255x over previous
//
#include <hip/hip_runtime.h>

#define N_NODES  100000
#define N_EDGES  1600000
#define N_GRAPHS 128
#define DD       64
#define EPSV     1e-5f

#define BSH      5          // bucket = dst >> 5  (32 nodes per bucket)
#define BMASK    31
#define NBUCK    3125       // 100000/32 exactly
#define NBPAD    4096       // hist padded to 4*1024 for the block scan
#define CAPB     768        // max bucket entries used downstream (mean 512, 11 sigma)

#define THRP     1024       // scatter block threads
#define EPT      16         // edges per thread
#define BLKE     (THRP*EPT) // 16384
#define NBLK     ((N_EDGES + BLKE - 1) / BLKE)   // 98

// workspace byte offsets
#define O_ORD   200704u     // int[NBLK*BLKE]  block-private bucket-sorted edges (6.42MB)
#define O_DESC  6754304u    // int[NBUCK*NBLK] TRANSPOSED: (start<<10)|cnt, contiguous per bucket
#define O_GACC  9801216u    // float[G*D]; bytes [9833984,9834496) = zero row (bf16 gather tails)
#define O_XB    9834496u    // ushort[N_NODES*DD]  bf16 copy of x
#define O_WTF   22634496u   // ushort[1024*8]  B-operand in MFMA fragment layout (16 KB)
#define O_XQZ   22650880u   // uint[64] zero row (fp8 gather tails) + uint[N_NODES*16] fp8 x
#define WS_NEED 29051136u

typedef __attribute__((ext_vector_type(8))) short bf16x8;
typedef __attribute__((ext_vector_type(4))) float f32x4;
typedef __attribute__((ext_vector_type(2))) float f32x2;

__device__ __forceinline__ ushort bf16rne(float f) {
  uint u = __float_as_uint(f);
  return (ushort)((u + 0x7FFFu + ((u >> 16) & 1u)) >> 16);
}
__device__ __forceinline__ uint pk2(float lo, float hi) {
  return (uint)bf16rne(lo) | ((uint)bf16rne(hi) << 16);
}

// full-grid fp32->bf16 cast of x + fp8 (e4m3) copy for the gather + zero inits
__global__ __launch_bounds__(256) void cast_k(const float* __restrict__ x, ushort* __restrict__ xb,
                                              float* __restrict__ gacc, uint* __restrict__ xq4) {
  int i = blockIdx.x * 256 + threadIdx.x;      // grid 6250*256 = 1.6M = N_NODES*DD/4 exactly
  if (i < N_GRAPHS * DD) gacc[i] = 0.f;
  if (i < 128) gacc[N_GRAPHS * DD + i] = 0.f;  // bf16 zero row gap (= xb - 512)
  float4 v = ((const float4*)x)[i];
  uint4 u = *(const uint4*)&v;
  ushort4 o;
  o.x = (ushort)((u.x + 0x7FFFu + ((u.x >> 16) & 1)) >> 16);
  o.y = (ushort)((u.y + 0x7FFFu + ((u.y >> 16) & 1)) >> 16);
  o.z = (ushort)((u.z + 0x7FFFu + ((u.z >> 16) & 1)) >> 16);
  o.w = (ushort)((u.w + 0x7FFFu + ((u.w >> 16) & 1)) >> 16);
  ((ushort4*)xb)[i] = o;
  if (xq4) {                                   // fp8 path enabled (ws large enough)
    uint q = 0;
    q = __builtin_amdgcn_cvt_pk_fp8_f32(v.x, v.y, q, false);
    q = __builtin_amdgcn_cvt_pk_fp8_f32(v.z, v.w, q, true);
    xq4[64 + i] = q;                           // [0..63] = 256B zero row
    if (i < 64) xq4[i] = 0u;
  }
}

// Per-block bucket sort with PRIVATE output regions — zero global atomics.
// ordered[blk*BLKE + rank]; desc[b*NBLK + blk] = (start<<10)|cnt (transposed).
// Block 0 also builds the MFMA B-operand image wtf.
__global__ __launch_bounds__(1024) void scatS_k(const int* __restrict__ ei,
                                                int* __restrict__ ordered,
                                                int* __restrict__ desc,
                                                const float* __restrict__ Wself,
                                                const float* __restrict__ Wneigh,
                                                ushort* __restrict__ wtf) {
  __shared__ int hist[NBPAD];
  __shared__ int cur2[NBPAD];
  __shared__ int wtot[16];
  int t = threadIdx.x;
  if (blockIdx.x == 0) {
    int lane = t & 63, ks = (t >> 6) & 3, tile = (t >> 8) & 1, nt = t >> 9;
    int brow = (nt << 5) + (tile << 4) + (lane & 15);
    int k0 = (ks << 5) + (((lane >> 4) & 3) << 3);
    uint4 o;
    uint p[4];
#pragma unroll
    for (int jj = 0; jj < 4; ++jj) {
      int k = k0 + jj * 2;
      float w0 = (k < 64)     ? Wself[k * DD + brow]       : Wneigh[(k - 64) * DD + brow];
      float w1 = (k + 1 < 64) ? Wself[(k + 1) * DD + brow] : Wneigh[(k - 63) * DD + brow];
      p[jj] = pk2(w0, w1);
    }
    o.x = p[0]; o.y = p[1]; o.z = p[2]; o.w = p[3];
    ((uint4*)wtf)[t] = o;
  }
  for (int i = t; i < NBPAD; i += THRP) hist[i] = 0;
  __syncthreads();
  int e0 = blockIdx.x * BLKE;
  int pk[EPT], bn[EPT];
#pragma unroll
  for (int j = 0; j < EPT; ++j) {
    int e = e0 + j * THRP + t;
    bn[j] = -1;
    if (e < N_EDGES) {
      int s = ei[e], d = ei[N_EDGES + e];
      bn[j] = d >> BSH;
      pk[j] = s | ((d & BMASK) << 17);
      atomicAdd(&hist[bn[j]], 1);
    }
  }
  __syncthreads();
  // block-wide exclusive scan over 4096 bins (thread t owns bins 4t..4t+3)
  int h0 = hist[4 * t], h1 = hist[4 * t + 1], h2 = hist[4 * t + 2], h3 = hist[4 * t + 3];
  int s = h0 + h1 + h2 + h3;
  int lane = t & 63, wv = t >> 6;
  int inc = s;
#pragma unroll
  for (int off = 1; off < 64; off <<= 1) {
    int u = __shfl_up(inc, off);
    if (lane >= off) inc += u;
  }
  if (lane == 63) wtot[wv] = inc;
  __syncthreads();
  if (t < 16) {
    int v = wtot[t];
    int iv = v;
#pragma unroll
    for (int off = 1; off < 16; off <<= 1) {
      int u = __shfl_up(iv, off);
      if (t >= off) iv += u;
    }
    wtot[t] = iv - v;   // exclusive wave base
  }
  __syncthreads();
  int base = wtot[wv] + (inc - s);
  cur2[4 * t]     = base;
  cur2[4 * t + 1] = base + h0;
  cur2[4 * t + 2] = base + h0 + h1;
  cur2[4 * t + 3] = base + h0 + h1 + h2;
  {
#pragma unroll
    for (int i = 0; i < 4; ++i) {
      int bb = 4 * t + i;
      if (bb < NBUCK) desc[bb * NBLK + blockIdx.x] = (cur2[bb] << 10) | hist[bb];
    }
  }
  __syncthreads();
  int obase = blockIdx.x * BLKE;
#pragma unroll
  for (int j = 0; j < EPT; ++j) {
    if (bn[j] >= 0) {
      int sp = atomicAdd(&cur2[bn[j]], 1);
      ordered[obase + sp] = pk[j];
    }
  }
}

// FUSED per-bucket kernel: coalesced descriptor row -> run-prefix scan -> per-entry
// binary-search loads -> counting-sort -> pull-based mean (fp8 or bf16 gathers)
// -> MFMA combine -> epilogue.
template <bool QF8>
__global__ __launch_bounds__(256, 8) void aggM_k(const ushort* __restrict__ xb,
                                                 const uint* __restrict__ xq4,
                                                 const int* __restrict__ ordered,
                                                 const int* __restrict__ desc,
                                                 const ushort* __restrict__ wtf,
                                                 const float* __restrict__ bvec,
                                                 const float* __restrict__ gamma,
                                                 const float* __restrict__ beta,
                                                 const int* __restrict__ batch,
                                                 float* __restrict__ gacc,
                                                 float* __restrict__ out) {
  __shared__ short As[32 * 128];    // 8KB: A=[xb|h] bf16 swizzled; LIVE through epilogue
  __shared__ float Cbuf[32 * 65];   // 8.3KB: MFMA C (padded rows)
  __shared__ int sorted[CAPB + 16]; // [0..127]=posA, [128..255]=stA during assembly; then slots
  __shared__ int hist[32], startc[32], curl[32];
  __shared__ int wsum2[2];
  __shared__ int nTot_s;
  int* posA = sorted;
  int* stA  = sorted + 128;
  int t = threadIdx.x;
  int b = blockIdx.x;
  int node0 = b << BSH;
  if (t < 32) hist[t] = 0;
  // stage A x-part (k=0..63): contiguous 4KB read of this bucket's xb rows
  {
    uint4 v = ((const uint4*)(xb + (size_t)node0 * DD))[t];   // t = r*8 + c
    uint r = (uint)t >> 3, c = (uint)t & 7;
    *(uint4*)((char*)As + r * 256u + ((c * 16u) ^ ((r & 7u) << 4))) = v;
  }
  // coalesced descriptor row + 128-thread scan of counts
  int dsc = (t < NBLK) ? desc[b * NBLK + t] : 0;
  int c   = dsc & 1023;
  int st  = dsc >> 10;
  int inc = c;
  if (t < 128) {
    int lane = t & 63;
#pragma unroll
    for (int off = 1; off < 64; off <<= 1) {
      int u = __shfl_up(inc, off);
      if (lane >= off) inc += u;
    }
    if (lane == 63) wsum2[t >> 6] = inc;
  }
  __syncthreads();
  if (t < 128) {
    int pos = ((t >> 6) ? wsum2[0] : 0) + inc - c;
    posA[t] = (t < NBLK) ? pos : 0x7FFFFFFF;
    stA[t]  = t * BLKE + st;
  }
  if (t == 0) nTot_s = wsum2[0] + wsum2[1];
  __syncthreads();
  int n = nTot_s;
  if (n > CAPB) n = CAPB;
  auto bs_load = [&](int i) -> int {
    int lo = 0;
#pragma unroll
    for (int stp = 64; stp; stp >>= 1) {
      int cnd = lo + stp;
      lo = (posA[cnd] <= i) ? cnd : lo;
    }
    return ordered[stA[lo] + (i - posA[lo])];
  };
  int w0 = -1, w1 = -1, w2 = -1;
  if (t < n)       { w0 = bs_load(t);       atomicAdd(&hist[w0 >> 17], 1); }
  if (t + 256 < n) { w1 = bs_load(t + 256); atomicAdd(&hist[w1 >> 17], 1); }
  if (t + 512 < n) { w2 = bs_load(t + 512); atomicAdd(&hist[w2 >> 17], 1); }
  __syncthreads();
  if (t < 32) {
    int h = hist[t];
    int v = h;
#pragma unroll
    for (int off = 1; off < 32; off <<= 1) {
      int u = __shfl_up(v, off);
      if (t >= off) v += u;
    }
    startc[t] = v - h;
    curl[t]   = v - h;
  }
  __syncthreads();
  // ranked slots: fp8 stores (idx<<6)+256 byte offsets, bf16 stores (idx<<7)+512
  if (w0 >= 0) { int p = atomicAdd(&curl[w0 >> 17], 1);
                 sorted[p] = QF8 ? (((w0 & 0x1FFFF) << 6) + 256) : (((w0 & 0x1FFFF) << 7) + 512); }
  if (w1 >= 0) { int p = atomicAdd(&curl[w1 >> 17], 1);
                 sorted[p] = QF8 ? (((w1 & 0x1FFFF) << 6) + 256) : (((w1 & 0x1FFFF) << 7) + 512); }
  if (w2 >= 0) { int p = atomicAdd(&curl[w2 >> 17], 1);
                 sorted[p] = QF8 ? (((w2 & 0x1FFFF) << 6) + 256) : (((w2 & 0x1FFFF) << 7) + 512); }
  __syncthreads();
  int wl   = __builtin_amdgcn_readfirstlane(t >> 6);
  int lane = t & 63;
  int g    = lane >> 4;     // edge-group 0..3
  int sub  = lane & 15;     // dim group: dims [sub*4, sub*4+4)
  const char* zb = QF8 ? (const char*)xq4 : ((const char*)xb - 512);  // +0 = zero row
  uint subb = QF8 ? ((uint)sub * 4u) : ((uint)sub * 8u);
  // pull aggregation: 4 edges per instruction x 4 loads in flight; mean -> A k=64..127
  for (int r = wl; r < 32; r += 4) {
    int s0 = startc[r], dg = hist[r];
    f32x2 A01 = {0.f, 0.f}, A23 = {0.f, 0.f};
    for (int j = 0; j < dg; j += 16) {
      int e0 = j + g, e1 = j + 4 + g, e2 = j + 8 + g, e3 = j + 12 + g;
      uint o0 = (uint)sorted[s0 + e0]; if (e0 >= dg) o0 = 0u;   // tail -> zero row
      uint o1 = (uint)sorted[s0 + e1]; if (e1 >= dg) o1 = 0u;
      uint o2 = (uint)sorted[s0 + e2]; if (e2 >= dg) o2 = 0u;
      uint o3 = (uint)sorted[s0 + e3]; if (e3 >= dg) o3 = 0u;
      if (QF8) {
        uint u0 = *(const uint*)(zb + o0 + subb);               // 1 line per 16-lane row
        uint u1 = *(const uint*)(zb + o1 + subb);
        uint u2 = *(const uint*)(zb + o2 + subb);
        uint u3 = *(const uint*)(zb + o3 + subb);
        f32x2 p0 = __builtin_amdgcn_cvt_pk_f32_fp8(u0, false);
        f32x2 p1 = __builtin_amdgcn_cvt_pk_f32_fp8(u1, false);
        f32x2 p2 = __builtin_amdgcn_cvt_pk_f32_fp8(u2, false);
        f32x2 p3 = __builtin_amdgcn_cvt_pk_f32_fp8(u3, false);
        f32x2 q0 = __builtin_amdgcn_cvt_pk_f32_fp8(u0, true);
        f32x2 q1 = __builtin_amdgcn_cvt_pk_f32_fp8(u1, true);
        f32x2 q2 = __builtin_amdgcn_cvt_pk_f32_fp8(u2, true);
        f32x2 q3 = __builtin_amdgcn_cvt_pk_f32_fp8(u3, true);
        A01 += (p0 + p1) + (p2 + p3);
        A23 += (q0 + q1) + (q2 + q3);
      } else {
        uint2 u0 = *(const uint2*)(zb + o0 + subb);
        uint2 u1 = *(const uint2*)(zb + o1 + subb);
        uint2 u2 = *(const uint2*)(zb + o2 + subb);
        uint2 u3 = *(const uint2*)(zb + o3 + subb);
        f32x2 v0, v1, v2, v3, y0, y1, y2, y3;
        v0.x = __uint_as_float(u0.x << 16); v0.y = __uint_as_float(u0.x & 0xFFFF0000u);
        v1.x = __uint_as_float(u1.x << 16); v1.y = __uint_as_float(u1.x & 0xFFFF0000u);
        v2.x = __uint_as_float(u2.x << 16); v2.y = __uint_as_float(u2.x & 0xFFFF0000u);
        v3.x = __uint_as_float(u3.x << 16); v3.y = __uint_as_float(u3.x & 0xFFFF0000u);
        y0.x = __uint_as_float(u0.y << 16); y0.y = __uint_as_float(u0.y & 0xFFFF0000u);
        y1.x = __uint_as_float(u1.y << 16); y1.y = __uint_as_float(u1.y & 0xFFFF0000u);
        y2.x = __uint_as_float(u2.y << 16); y2.y = __uint_as_float(u2.y & 0xFFFF0000u);
        y3.x = __uint_as_float(u3.y << 16); y3.y = __uint_as_float(u3.y & 0xFFFF0000u);
        A01 += (v0 + v1) + (v2 + v3);
        A23 += (y0 + y1) + (y2 + y3);
      }
    }
    float a0 = A01.x, a1 = A01.y, a2 = A23.x, a3 = A23.y;
#pragma unroll
    for (int off = 16; off <= 32; off <<= 1) {
      a0 += __shfl_xor(a0, off);
      a1 += __shfl_xor(a1, off);
      a2 += __shfl_xor(a2, off);
      a3 += __shfl_xor(a3, off);
    }
    if (g == 0) {
      float inv = 1.f / fmaxf((float)dg, 1.f);
      uint2 pw;
      pw.x = pk2(a0 * inv, a1 * inv);
      pw.y = pk2(a2 * inv, a3 * inv);
      uint rr = (uint)r;
      *(uint2*)((char*)As + rr * 256u + ((128u + (uint)sub * 8u) ^ ((rr & 7u) << 4))) = pw;
    }
  }
  __syncthreads();
  // MFMA combine: wave -> (mrow, n-tile pair); B fragments streamed from global (L2-hot)
  f32x4 acc0 = {0.f, 0.f, 0.f, 0.f}, acc1 = {0.f, 0.f, 0.f, 0.f};
  uint mrow  = (uint)(wl >> 1) << 4;   // 0 / 16
  int  nt    = wl & 1;
  uint arow  = mrow + (uint)(lane & 15);
  uint kc    = ((uint)(lane >> 4)) * 16u;
#pragma unroll 1
  for (int ks = 0; ks < 4; ++ks) {
    uint kb = (uint)ks * 64u + kc;
    bf16x8 af = *(const bf16x8*)((const char*)As + arow * 256u + (kb ^ ((arow & 7u) << 4)));
    bf16x8 b0 = *(const bf16x8*)(wtf + (size_t)(((nt * 2 + 0) * 4 + ks) * 64 + lane) * 8);
    bf16x8 b1 = *(const bf16x8*)(wtf + (size_t)(((nt * 2 + 1) * 4 + ks) * 64 + lane) * 8);
    acc0 = __builtin_amdgcn_mfma_f32_16x16x32_bf16(af, b0, acc0, 0, 0, 0);
    acc1 = __builtin_amdgcn_mfma_f32_16x16x32_bf16(af, b1, acc1, 0, 0, 0);
  }
  // write C to the padded buffer (As stays live for the residual)
  {
    uint nbase = (uint)nt << 5;
    uint rr = mrow + (((uint)(lane >> 4)) << 2);
    uint cc = nbase + (uint)(lane & 15);
#pragma unroll
    for (int j = 0; j < 4; ++j) {
      uint rj = rr + (uint)j;
      Cbuf[rj * 65u + cc]       = acc0[j];
      Cbuf[rj * 65u + cc + 16u] = acc1[j];
    }
  }
  __syncthreads();
  // epilogue: bias, graph pooling (sorted batch), residual (bf16 x from LDS), LN, ReLU
  float bv  = bvec[lane];
  float gv  = gamma[lane];
  float btv = beta[lane];
  int r0 = wl * 8;
  int gprev = -1; float pool = 0.f;
#pragma unroll
  for (int m = 0; m < 8; ++m) {
    uint r = (uint)(r0 + m);
    int node = node0 + r0 + m;
    float cval = Cbuf[r * 65u + (uint)lane];
    float tmp = cval + bv;
    int gi = batch[node];
    if (gi != gprev) {
      if (gprev >= 0) atomicAdd(&gacc[gprev * DD + lane], pool);
      pool = 0.f; gprev = gi;
    }
    pool += tmp;
    ushort xv16 = *(const ushort*)((const char*)As + r * 256u + (((uint)lane * 2u) ^ ((r & 7u) << 4)));
    float val = tmp + __uint_as_float((uint)xv16 << 16);
    float s = val;
    for (int off = 32; off; off >>= 1) s += __shfl_xor(s, off);
    float mu  = s * (1.f / 64.f);
    float dlt = val - mu;
    float ss  = dlt * dlt;
    for (int off = 32; off; off >>= 1) ss += __shfl_xor(ss, off);
    float rstd = rsqrtf(ss * (1.f / 64.f) + EPSV);
    float o = dlt * rstd * gv + btv;
    out[(size_t)node * DD + lane] = fmaxf(o, 0.f);
  }
  if (gprev >= 0) atomicAdd(&gacc[gprev * DD + lane], pool);
}

__global__ __launch_bounds__(256) void graph_k(const float* __restrict__ gacc, const float* __restrict__ gemb,
                                               const float* __restrict__ gamma, const float* __restrict__ beta,
                                               float* __restrict__ out) {
  int lane = threadIdx.x & 63;
  int w = blockIdx.x * 4 + (threadIdx.x >> 6);
  if (w >= N_GRAPHS) return;
  float v = gacc[w * DD + lane] + gemb[w * DD + lane];
  float gv = gamma[lane], btv = beta[lane];
#pragma unroll
  for (int it = 0; it < 2; ++it) {
    float s = v;
    for (int off = 32; off; off >>= 1) s += __shfl_xor(s, off);
    float mu  = s * (1.f / 64.f);
    float d   = v - mu;
    float ss  = d * d;
    for (int off = 32; off; off >>= 1) ss += __shfl_xor(ss, off);
    v = d * rsqrtf(ss * (1.f / 64.f) + EPSV) * gv + btv;
  }
  out[(size_t)N_NODES * DD + w * DD + lane] = v;
}

extern "C" void kernel_launch(void* const* d_in, const int* in_sizes, int n_in,
                              void* d_out, int out_size, void* d_ws, size_t ws_size,
                              hipStream_t stream) {
  const float* x      = (const float*)d_in[0];
  const int*   ei     = (const int*)d_in[1];
  const int*   batch  = (const int*)d_in[2];
  const float* gemb   = (const float*)d_in[3];
  const float* Wself  = (const float*)d_in[4];
  const float* Wneigh = (const float*)d_in[5];
  const float* bvec   = (const float*)d_in[6];
  const float* gamma  = (const float*)d_in[7];
  const float* beta   = (const float*)d_in[8];

  char* ws = (char*)d_ws;
  int*    ordered = (int*)(ws + O_ORD);
  int*    desc    = (int*)(ws + O_DESC);
  float*  gacc    = (float*)(ws + O_GACC);
  ushort* xb      = (ushort*)(ws + O_XB);
  ushort* wtf     = (ushort*)(ws + O_WTF);
  uint*   xq4     = (uint*)(ws + O_XQZ);
  float*  outf    = (float*)d_out;

  bool q8 = ws_size >= WS_NEED;
  cast_k <<<N_NODES * DD / 4 / 256, 256, 0, stream>>>(x, xb, gacc, q8 ? xq4 : nullptr);
  scatS_k<<<NBLK, THRP, 0, stream>>>(ei, ordered, desc, Wself, Wneigh, wtf);
  if (q8)
    aggM_k<true><<<NBUCK, 256, 0, stream>>>(xb, xq4, ordered, desc, wtf, bvec, gamma, beta,
                                            batch, gacc, outf);
  else
    aggM_k<false><<<NBUCK, 256, 0, stream>>>(xb, xq4, ordered, desc, wtf, bvec, gamma, beta,
                                             batch, gacc, outf);
  graph_k<<<N_GRAPHS / 4, 256, 0, stream>>>(gacc, gemb, gamma, beta, outf);
}